// Round 7
// baseline (688.464 us; speedup 1.0000x reference)
//
#include <hip/hip_runtime.h>

typedef int v4i __attribute__((ext_vector_type(4)));

#define BM 256
#define BN 256
#define BKB 64  // K-bytes per step (i8 elems)

// ---------- preprocessing ----------

__device__ __forceinline__ float max4abs(float4 v) {
  return fmaxf(fmaxf(fabsf(v.x), fabsf(v.y)), fmaxf(fabsf(v.z), fabsf(v.w)));
}

__device__ __forceinline__ int packq4(float4 v, float inv) {
  int b0 = ((int)fminf(127.f, fmaxf(-127.f, rintf(v.x * inv)))) & 255;
  int b1 = ((int)fminf(127.f, fmaxf(-127.f, rintf(v.y * inv)))) & 255;
  int b2 = ((int)fminf(127.f, fmaxf(-127.f, rintf(v.z * inv)))) & 255;
  int b3 = ((int)fminf(127.f, fmaxf(-127.f, rintf(v.w * inv)))) & 255;
  return b0 | (b1 << 8) | (b2 << 16) | (b3 << 24);
}

// Fused: blocks [0,nrows) per-row i8-quantize x; blocks [nrows,nrows+1024) reduce
// max|W|; last block reduces max|b|. All independent -> one dispatch.
__global__ void prep1_kernel(const float4* __restrict__ X4,
                             signed char* __restrict__ Q,
                             float* __restrict__ sx, int K, int nrows,
                             const float4* __restrict__ W4, long nW4,
                             const float4* __restrict__ b4, int nb4,
                             unsigned* __restrict__ mx) {
  __shared__ float sm[4];
  const int tid = threadIdx.x;
  const int bid = blockIdx.x;

  if (bid < nrows) {  // ---- xquant: one block per row, K==4096 assumed
    const float4* xr = X4 + (size_t)bid * (K / 4);
    float4 v0 = xr[tid], v1 = xr[tid + 256], v2 = xr[tid + 512], v3 = xr[tid + 768];
    float m = fmaxf(fmaxf(max4abs(v0), max4abs(v1)), fmaxf(max4abs(v2), max4abs(v3)));
    for (int off = 32; off > 0; off >>= 1) m = fmaxf(m, __shfl_down(m, off));
    if ((tid & 63) == 0) sm[tid >> 6] = m;
    __syncthreads();
    const float total = fmaxf(fmaxf(sm[0], sm[1]), fmaxf(sm[2], sm[3]));
    const float inv = 127.f / total;
    int* qw = (int*)(Q + (size_t)bid * K);
    qw[tid]       = packq4(v0, inv);
    qw[tid + 256] = packq4(v1, inv);
    qw[tid + 512] = packq4(v2, inv);
    qw[tid + 768] = packq4(v3, inv);
    if (tid == 0) sx[bid] = total * (1.f / 127.f);
    return;
  }

  // ---- absmax reductions
  float m = 0.f;
  const bool isB = (bid == gridDim.x - 1);
  if (!isB) {
    const long wb = bid - nrows;           // 0..1023
    const long stride = 1024L * blockDim.x;
    for (long i = wb * blockDim.x + tid; i < nW4; i += stride)
      m = fmaxf(m, max4abs(W4[i]));
  } else {
    for (int i = tid; i < nb4; i += blockDim.x) m = fmaxf(m, max4abs(b4[i]));
  }
  for (int off = 32; off > 0; off >>= 1) m = fmaxf(m, __shfl_down(m, off));
  if ((tid & 63) == 0) sm[tid >> 6] = m;
  __syncthreads();
  if (tid == 0) {
    m = fmaxf(fmaxf(sm[0], sm[1]), fmaxf(sm[2], sm[3]));
    atomicMax(mx + (isB ? 1 : 0), __float_as_uint(m));  // nonneg: uint order == float
  }
}

// Ternarize W -> i8{-1,0,1} (packed dword per float4, coalesced); last block: b -> fp32.
__global__ void prep_w_kernel(const float4* __restrict__ W4, long nW4,
                              const float4* __restrict__ b4, int nb4,
                              const unsigned* __restrict__ mx,
                              const float* __restrict__ bscale,
                              int* __restrict__ Twi, float4* __restrict__ bt) {
  if (blockIdx.x == gridDim.x - 1) {  // bias block
    const float delta = 0.05f * __uint_as_float(mx[1]);
    const float s = *bscale;
    for (int i = threadIdx.x; i < nb4; i += blockDim.x) {
      float4 v = b4[i];
      float4 o;
      o.x = v.x > delta ? s : (v.x < -delta ? -s : 0.f);
      o.y = v.y > delta ? s : (v.y < -delta ? -s : 0.f);
      o.z = v.z > delta ? s : (v.z < -delta ? -s : 0.f);
      o.w = v.w > delta ? s : (v.w < -delta ? -s : 0.f);
      bt[i] = o;
    }
    return;
  }
  const float delta = 0.05f * __uint_as_float(mx[0]);
  const long stride = (long)(gridDim.x - 1) * blockDim.x;
  for (long i = blockIdx.x * (long)blockDim.x + threadIdx.x; i < nW4; i += stride) {
    float4 w = W4[i];
    int b0 = w.x > delta ? 1 : (w.x < -delta ? 0xFF : 0);
    int b1 = w.y > delta ? 1 : (w.y < -delta ? 0xFF : 0);
    int b2 = w.z > delta ? 1 : (w.z < -delta ? 0xFF : 0);
    int b3 = w.w > delta ? 1 : (w.w < -delta ? 0xFF : 0);
    Twi[i] = b0 | (b1 << 8) | (b2 << 16) | (b3 << 24);
  }
}

// ---------- GEMM: C[m,n] = ws*sx[m]*(sum_k Aq[m,k]*T[n,k]) + bt[n], exact i32 acc ----
// NO-LDS direct-register GEMM. 256x256 tile, 8 waves (2Mx4N), wave tile 128x64 via
// 8x4 grid of 16x16x64 i8 MFMAs. Every fragment is loaded global->VGPR with
// global_load_dwordx4 (uniform SGPR base per mt/nt row-group + one per-lane
// voffset); the per-CU per-step fragment set (A 16KB + B 16KB) is L1-sized, and
// A/B panels are L2/L3-resident (48 MB quantized), so LDS staging is pure overhead:
// it cost 96KB/step of LDS reads + 32KB writes + 2 barriers + lgkm waits, and
// barrier-lockstep serialized the LDS and MFMA pipes (R6 measured 2457 cyc/step
// vs walls of 1306 MFMA / 1400 LDS). Here: no barriers in the K-loop (one light
// s_barrier every 8 steps keeps block waves phase-close so L1 serves the 4x A /
// 2x B intra-block sharing), full af/bf double-buffer (1-step prefetch hides
// L2-hit latency under 1306 cyc of MFMA), compiler auto-inserts exact vmcnt for
// the register RAW deps. Fragment data layout identical to the verified LDS path
// (chunk quad of each row), so MFMA mapping is unchanged.
__global__ __launch_bounds__(512, 2) void gemm_tern_i8(
    const signed char* __restrict__ A,   // [M,K] i8 quantized x
    const signed char* __restrict__ B,   // [N,K] i8 ternary {-1,0,1}
    const float* __restrict__ sx,        // [M] per-row x scale
    const float* __restrict__ bt,        // [N]
    const float* __restrict__ wsc,       // scalar
    float* __restrict__ C,               // [M,N] fp32
    int M, int N, int K) {
  const int tid = threadIdx.x;
  const int wave = tid >> 6;
  const int lane = tid & 63;
  const int wm = wave >> 2, wn = wave & 3;  // 2 x 4 wave grid
  const int quad = lane >> 4;               // 0..3
  const int l16 = lane & 15;

  // XCD-aware bijective swizzle: 512 wgs, 8 XCDs -> 4-M-row band each, col-major
  // inside (kept since R2: FETCH 147->98 MB).
  const unsigned orig = blockIdx.x;
  const unsigned xcd = orig & 7;
  const unsigned r8 = orig >> 3;            // 0..63
  const int by = (int)(xcd * 4 + (r8 & 3)); // 0..31  (M)
  const int bx = (int)(r8 >> 2);            // 0..15  (N)
  const int bm0 = by * BM;
  const int bn0 = bx * BN;

  // per-lane voffsets (constant): row (tilebase + l16), 16B chunk = quad
  const unsigned aoff0 = (unsigned)((bm0 + wm * 128 + l16) * K + quad * 16);
  const unsigned boff0 = (unsigned)((bn0 + wn * 64 + l16) * K + quad * 16);

  const signed char* Ak = A;  // advances 64 B per K-step (uniform)
  const signed char* Bk = B;

  v4i afP[8], bfP[4], afQ[8], bfQ[4];
  v4i acc[8][4] = {};

// load fragments of the step Ak/Bk currently point at, then advance one step.
// mt*16*K / nt*16*K are uniform -> SGPR base adds; aoff0/boff0 the only voffsets.
#define LDF(AF, BF)                                                   \
  do {                                                                \
    _Pragma("unroll")                                                 \
    for (int mt = 0; mt < 8; ++mt)                                    \
      AF[mt] = *(const v4i*)(Ak + ((unsigned)(mt * 16) * K + aoff0)); \
    _Pragma("unroll")                                                 \
    for (int nt = 0; nt < 4; ++nt)                                    \
      BF[nt] = *(const v4i*)(Bk + ((unsigned)(nt * 16) * K + boff0)); \
    Ak += BKB;                                                        \
    Bk += BKB;                                                        \
  } while (0)

#define MM(AF, BF)                                                            \
  do {                                                                        \
    __builtin_amdgcn_s_setprio(1);                                            \
    _Pragma("unroll")                                                         \
    for (int mt = 0; mt < 8; ++mt)                                            \
      _Pragma("unroll")                                                       \
      for (int nt = 0; nt < 4; ++nt)                                          \
        acc[mt][nt] = __builtin_amdgcn_mfma_i32_16x16x64_i8(                  \
            AF[mt], BF[nt], acc[mt][nt], 0, 0, 0);                            \
    __builtin_amdgcn_s_setprio(0);                                            \
  } while (0)

// half-step interleave pin: 12 VMEM loads, then 32 MFMA
#define SGB(m, n) __builtin_amdgcn_sched_group_barrier((m), (n), 0)
#define PIN() do { SGB(0x20, 12); SGB(0x8, 32); } while (0)

  LDF(afP, bfP);  // step 0
  for (int t = 0; t < 62; t += 2) {
    LDF(afQ, bfQ);  // step t+1
    MM(afP, bfP);   // step t   (compiler emits vmcnt(12): P retired, Q in flight)
    PIN();
    LDF(afP, bfP);  // step t+2
    MM(afQ, bfQ);   // step t+1
    PIN();
    if ((t & 7) == 6) __builtin_amdgcn_s_barrier();  // every 8 steps: phase-align
  }
  // tail: P holds step 62
  LDF(afQ, bfQ);  // step 63
  MM(afP, bfP);
  PIN();
  MM(afQ, bfQ);

#undef LDF
#undef MM
#undef SGB
#undef PIN

  // epilogue: D layout col=lane&15, row=quad*4+reg (shape-determined, dtype-indep)
  const float ws = *wsc;
#pragma unroll
  for (int mt = 0; mt < 8; ++mt) {
    const int row = bm0 + wm * 128 + mt * 16 + quad * 4;
    float sc[4];
#pragma unroll
    for (int r = 0; r < 4; ++r) sc[r] = ws * sx[row + r];
#pragma unroll
    for (int nt = 0; nt < 4; ++nt) {
      const int col = bn0 + wn * 64 + nt * 16 + l16;
      const float bias = bt[col];
#pragma unroll
      for (int r = 0; r < 4; ++r)
        C[(size_t)(row + r) * N + col] = sc[r] * (float)acc[mt][nt][r] + bias;
    }
  }
}

// ---------- launch ----------

extern "C" void kernel_launch(void* const* d_in, const int* in_sizes, int n_in,
                              void* d_out, int out_size, void* d_ws, size_t ws_size,
                              hipStream_t stream) {
  const float* x = (const float*)d_in[0];
  const float* W = (const float*)d_in[1];
  const float* w_scale = (const float*)d_in[2];
  const float* b = (const float*)d_in[3];
  const float* b_scale = (const float*)d_in[4];
  float* out = (float*)d_out;

  const int K = 4096;             // D_IN
  const int N = in_sizes[3];      // D_OUT = 4096
  const int M = in_sizes[0] / K;  // B*S = 8192

  // workspace layout
  char* ws = (char*)d_ws;
  signed char* xb = (signed char*)ws;                        // M*K i8 (32 MB)
  signed char* Tw = (signed char*)(ws + (size_t)M * K);      // N*K i8 (16 MB)
  float* bt = (float*)(ws + (size_t)M * K + (size_t)N * K);  // N fp32
  float* sx = bt + N;                                        // M fp32
  unsigned* mx = (unsigned*)(sx + M);                        // [0]=max|W|,[1]=max|b|

  hipMemsetAsync(mx, 0, 8, stream);

  const long nW4 = (long)N * K / 4;
  const int nb4 = N / 4;

  // fused xquant + absmax(W) + absmax(b): 8192 + 1024 + 1 blocks
  prep1_kernel<<<M + 1024 + 1, 256, 0, stream>>>((const float4*)x, xb, sx, K, M,
                                                 (const float4*)W, nW4,
                                                 (const float4*)b, nb4, mx);

  prep_w_kernel<<<2049, 256, 0, stream>>>((const float4*)W, nW4,
                                          (const float4*)b, nb4, mx, b_scale,
                                          (int*)Tw, (float4*)bt);

  const int nwg = (N / BN) * (M / BM);  // 16 * 32 = 512, divisible by 8
  gemm_tern_i8<<<nwg, 512, 0, stream>>>(xb, Tw, sx, bt, w_scale, out, M, N, K);
}